// Round 9
// baseline (127.865 us; speedup 1.0000x reference)
//
#include <hip/hip_runtime.h>
#include <hip/hip_bf16.h>
#include <stdint.h>

typedef __attribute__((ext_vector_type(8))) __bf16 bf16x8;
typedef __attribute__((ext_vector_type(4))) float f32x4;

constexpr int Bn = 4096;   // batch
constexpr int Dd = 1024;   // feature dim
constexpr int Cc = 1000;   // classes
constexpr int PANEL_ELEMS = 128 * Dd;   // 128-row panel (131072 elems, 256 KB)
constexpr int NTK = Dd / 64;            // 16 K-tiles of BK=64

__device__ __forceinline__ float wsum(float v) {
#pragma unroll
  for (int m = 32; m >= 1; m >>= 1) v += __shfl_xor(v, m);
  return v;
}
__device__ __forceinline__ float wmax(float v) {
#pragma unroll
  for (int m = 32; m >= 1; m >>= 1) v = fmaxf(v, __shfl_xor(v, m));
  return v;
}

// ---- fused: normalize -> tiled-bf16 xnt | CE rows | first-occurrence scan ----
// xnt layout: panel p = row>>7 (128 rows); within panel: [kt16][kk8][row128][e8]
//   kt = k>>6, kk = ((k>>5)&1)*4 + ((k>>3)&3), e = k&7.
// => each 128-row x 64-k half-tile is contiguous 16 KB, image = [kk][row][8]
//    (fragment-ready for mfma 16x16x32, conflict-free ds_read_b128; R1/R3-validated).
__global__ void prep_kernel(const float* __restrict__ data, const float* __restrict__ x,
                            const int* __restrict__ y, unsigned short* __restrict__ xnt,
                            float* __restrict__ celogp, float* __restrict__ total,
                            int* __restrict__ first_occ) {
  __shared__ float red[4];
  __shared__ float red2[4];
  __shared__ int fo[Cc];
  int b = blockIdx.x;
  int t = threadIdx.x;
  if (b < Bn) {
    if (t == 0) total[b] = 0.0f;
    const float4* xr = (const float4*)(x + (size_t)b * Dd);
    float4 v = xr[t];                       // 256 threads * 4 floats
    float ss = v.x * v.x + v.y * v.y + v.z * v.z + v.w * v.w;
    ss = wsum(ss);
    if ((t & 63) == 0) red[t >> 6] = ss;
    __syncthreads();
    float inv = 1.0f / fmaxf(sqrtf(red[0] + red[1] + red[2] + red[3]), 1e-8f);
    float f[4] = {v.x * inv, v.y * inv, v.z * inv, v.w * inv};
    ushort4 o;
    unsigned short* op = (unsigned short*)&o;
#pragma unroll
    for (int k = 0; k < 4; k++) {          // f32 -> bf16 RNE
      unsigned u = __float_as_uint(f[k]);
      u += 0x7fffu + ((u >> 16) & 1u);
      op[k] = (unsigned short)(u >> 16);
    }
    int p = b >> 7, rl = b & 127;
    int k0 = t * 4;
    int kt = k0 >> 6, kk = ((k0 >> 5) & 1) * 4 + ((k0 >> 3) & 3), e = k0 & 7;  // e in {0,4}
    *(ushort4*)(xnt + (size_t)p * PANEL_ELEMS + kt * 8192 + kk * 1024 + rl * 8 + e) = o;
  } else if (b < 2 * Bn) {
    int i = b - Bn;
    const float* row = data + (size_t)i * Cc;
    float m = -1e30f;
    for (int c = t; c < Cc; c += 256) m = fmaxf(m, row[c]);
    m = wmax(m);
    if ((t & 63) == 0) red[t >> 6] = m;
    __syncthreads();
    m = fmaxf(fmaxf(red[0], red[1]), fmaxf(red[2], red[3]));
    float s = 0.f;
    for (int c = t; c < Cc; c += 256) s += __expf(row[c] - m);
    s = wsum(s);
    if ((t & 63) == 0) red2[t >> 6] = s;
    __syncthreads();
    if (t == 0) {
      float tot = red2[0] + red2[1] + red2[2] + red2[3];
      celogp[i] = -(row[y[i]] - m - logf(tot));
    }
  } else {
    for (int c = t; c < Cc; c += 256) fo[c] = 0x7fffffff;
    __syncthreads();
    for (int i = t; i < Bn; i += 256) atomicMin(&fo[y[i]], i);
    __syncthreads();
    for (int c = t; c < Cc; c += 256) first_occ[c] = fo[c];
  }
}

__device__ __forceinline__ void gload16(const void* g, void* l) {
  __builtin_amdgcn_global_load_lds((const __attribute__((address_space(1))) void*)g,
                                   (__attribute__((address_space(3))) void*)l, 16, 0, 0);
}

// ---- 8-phase 256^2 fused GEMM (T3+T4+T5): S = xn @ xn^T with exp-rowsum epilogue ----
// 256 blocks (1/CU), 512 thr = 8 waves (2M x 4N). BK=64, 16 K-tiles.
// LDS 128KB: [parity2][half4: A0,A1,B0,B1][16KB]. Per tile: 4 phases
//   {ds_read subtile | stage 1 half-tile | barrier | lgkm(0) | prio1 | 16 MFMA | prio0 | barrier}
// vmcnt(6) once per tile (3 half-tiles in flight, never drained).
// Slot-safety: each half is LDS-read in exactly ONE phase (frags reused from regs after),
// and its overwrite-stage is issued in a strictly later phase.
__global__ __launch_bounds__(512, 2) void gemm8_kernel(
    const __bf16* __restrict__ xnt, const int* __restrict__ y,
    const int* __restrict__ first_occ, float* __restrict__ total,
    float* __restrict__ posdot) {
  __shared__ __align__(16) __bf16 lds[2][4][8192];
  const int t = threadIdx.x, lane = t & 63, w = t >> 6;
  const int wr = w >> 2, wc = w & 3;               // 2 x 4 wave grid
  const int bi = blockIdx.x & 15, bj = blockIdx.x >> 4;
  const int kg = lane >> 4, fr = lane & 15;
  const __bf16* panA0 = xnt + (size_t)(2 * bi) * PANEL_ELEMS;
  const __bf16* panA1 = panA0 + PANEL_ELEMS;
  const __bf16* panB0 = xnt + (size_t)(2 * bj) * PANEL_ELEMS;
  const __bf16* panB1 = panB0 + PANEL_ELEMS;
  const int du = (t & ~63) * 8;                    // wave-uniform LDS dest (elems)
  const int aoff = kg * 1024 + (wr * 64 + fr) * 8; // A frag base within half
  const int boff = kg * 1024 + (wc * 32 + fr) * 8; // B frag base within half

  bf16x8 af[4][2], rb0[2][2], rb1[2][2];
  f32x4 acc[2][2][4][2] = {};

#define STAGE(pan, hs, kt, par)                                      \
  do {                                                               \
    const __bf16* s_ = (pan) + (kt) * 8192 + t * 8;                  \
    gload16(s_, &lds[par][hs][du]);                                  \
    gload16(s_ + 4096, &lds[par][hs][du + 4096]);                    \
  } while (0)
#define RDA(par, mh)                                                               \
  do {                                                                             \
    _Pragma("unroll") for (int mi = 0; mi < 4; ++mi)                               \
    _Pragma("unroll") for (int s = 0; s < 2; ++s)                                  \
      af[mi][s] = *(const bf16x8*)&lds[par][mh][aoff + s * 4096 + mi * 128];       \
  } while (0)
#define RDB(par, nh, br)                                                           \
  do {                                                                             \
    _Pragma("unroll") for (int nj = 0; nj < 2; ++nj)                               \
    _Pragma("unroll") for (int s = 0; s < 2; ++s)                                  \
      br[nj][s] = *(const bf16x8*)&lds[par][2 + nh][boff + s * 4096 + nj * 128];   \
  } while (0)
#define MM(mh, nh, br)                                                             \
  do {                                                                             \
    _Pragma("unroll") for (int mi = 0; mi < 4; ++mi)                               \
    _Pragma("unroll") for (int nj = 0; nj < 2; ++nj)                               \
    _Pragma("unroll") for (int s = 0; s < 2; ++s)                                  \
      acc[mh][nh][mi][nj] = __builtin_amdgcn_mfma_f32_16x16x32_bf16(               \
          af[mi][s], br[nj][s], acc[mh][nh][mi][nj], 0, 0, 0);                     \
  } while (0)
#define BAR() __builtin_amdgcn_s_barrier()
#define PIN() __builtin_amdgcn_sched_barrier(0)
#define WL()                                   \
  do {                                         \
    asm volatile("s_waitcnt lgkmcnt(0)");      \
    PIN();                                     \
  } while (0)
#define WV6()                                        \
  do {                                               \
    asm volatile("s_waitcnt vmcnt(6)" ::: "memory"); \
    PIN();                                           \
  } while (0)

  // ---- prologue: tile 0 complete (8 loads) + A0,B0,A1 of tile 1 (6 loads) ----
  STAGE(panA0, 0, 0, 0); STAGE(panA1, 1, 0, 0); STAGE(panB0, 2, 0, 0); STAGE(panB1, 3, 0, 0);
  STAGE(panA0, 0, 1, 1); STAGE(panB0, 2, 1, 1); STAGE(panA1, 1, 1, 1);
  WV6();   // oldest 8 done -> tile 0 resident; 6 in flight
  BAR();

  // ---- main loop: 16 K-tiles x 4 phases (unroll 2 => 8-phase iter, const parity) ----
#pragma unroll 2
  for (int T = 0; T < NTK; ++T) {
    const int par = T & 1;
    const int nx = (T + 1) & 15, px = (T + 1) & 1;
    const int n2 = (T + 2) & 15;                   // wrapped tail stages: harmless, keeps vmcnt exact
    // p0: reads A0,B0 ; stages B1(T+1)
    RDA(par, 0); RDB(par, 0, rb0);
    STAGE(panB1, 3, nx, px);
    BAR(); WL();
    __builtin_amdgcn_s_setprio(1); MM(0, 0, rb0); __builtin_amdgcn_s_setprio(0);
    PIN(); BAR();
    // p1: reads B1 ; stages A0(T+2)  [A0 slot last read at p0 -> safe]
    RDB(par, 1, rb1);
    STAGE(panA0, 0, n2, par);
    BAR(); WL();
    __builtin_amdgcn_s_setprio(1); MM(0, 1, rb1); __builtin_amdgcn_s_setprio(0);
    PIN(); BAR();
    // p2: reads A1 ; stages B0(T+2)  [B0 slot last read at p0 -> safe]
    RDA(par, 1);
    STAGE(panB0, 2, n2, par);
    BAR(); WL();
    __builtin_amdgcn_s_setprio(1); MM(1, 0, rb0); __builtin_amdgcn_s_setprio(0);
    PIN(); BAR();
    // p3: no reads ; stages A1(T+2)  [A1 slot last read at p2 -> safe] ; vmcnt(6)
    STAGE(panA1, 1, n2, par);
    BAR(); WL();
    __builtin_amdgcn_s_setprio(1); MM(1, 1, rb1); __builtin_amdgcn_s_setprio(0);
    PIN();
    WV6();   // tile T+1 fully resident; 3 half-tiles (6 loads) stay in flight
    BAR();
  }
#undef STAGE
#undef RDA
#undef RDB
#undef MM

  // ---- epilogue: total[r] += sum_c exp(2*S[r,c]) ; posdot[c] = S[jstar[c],c] ----
  const float c2 = 2.885390081777927f;
  const int rgrp = lane >> 4, cl = lane & 15;
  int cidx[2][2], jst[2][2];
#pragma unroll
  for (int nh = 0; nh < 2; ++nh)
#pragma unroll
    for (int nj = 0; nj < 2; ++nj) {
      cidx[nh][nj] = bj * 256 + nh * 128 + wc * 32 + nj * 16 + cl;
      jst[nh][nj] = first_occ[y[cidx[nh][nj]]];
    }
#pragma unroll
  for (int mh = 0; mh < 2; ++mh)
#pragma unroll
    for (int mi = 0; mi < 4; ++mi) {
      int rb = bi * 256 + mh * 128 + wr * 64 + mi * 16 + rgrp * 4;
#pragma unroll
      for (int j = 0; j < 4; ++j) {
        int r = rb + j;
        float rs = 0.f;
#pragma unroll
        for (int nh = 0; nh < 2; ++nh)
#pragma unroll
          for (int nj = 0; nj < 2; ++nj) {
            float v = acc[mh][nh][mi][nj][j];
            rs += exp2f(v * c2);
            if (jst[nh][nj] == r) posdot[cidx[nh][nj]] = v;  // unique (r,c) globally
          }
#pragma unroll
        for (int m = 1; m <= 8; m <<= 1) rs += __shfl_xor(rs, m);  // over 16 col-lanes
        if (cl == 0) atomicAdd(&total[r], rs);
      }
    }
}

// ---- final reduction ----
__global__ void finalize_kernel(const float* __restrict__ total, const float* __restrict__ posdot,
                                const float* __restrict__ celogp, float* __restrict__ out) {
  int t = threadIdx.x;  // 1024 threads
  float fs = 0.f, cs = 0.f;
  for (int i = t; i < Bn; i += 1024) {
    fs += logf(total[i]) - 2.0f * posdot[i];
    cs += celogp[i];
  }
  fs = wsum(fs);
  cs = wsum(cs);
  __shared__ float rf[16], rc[16];
  if ((t & 63) == 0) { rf[t >> 6] = fs; rc[t >> 6] = cs; }
  __syncthreads();
  if (t == 0) {
    float lf = 0.f, la = 0.f;
#pragma unroll
    for (int w = 0; w < 16; w++) { lf += rf[w]; la += rc[w]; }
    lf /= (float)Bn;
    la /= (float)Bn;
    out[0] = la + 0.05f * lf;
    out[1] = la;
    out[2] = lf;
  }
}

extern "C" void kernel_launch(void* const* d_in, const int* in_sizes, int n_in,
                              void* d_out, int out_size, void* d_ws, size_t ws_size,
                              hipStream_t stream) {
  const float* data = (const float*)d_in[0];
  const float* x = (const float*)d_in[1];
  const int* y = (const int*)d_in[2];
  char* ws = (char*)d_ws;
  unsigned short* xn = (unsigned short*)ws;                       // 8 MB bf16, tiled layout
  float* total = (float*)(ws + (size_t)8 * 1024 * 1024);          // 16 KB
  float* posdot = total + Bn;                                     // 16 KB
  float* celogp = posdot + Bn;                                    // 16 KB
  int* first_occ = (int*)(celogp + Bn);                           // 4 KB
  float* out = (float*)d_out;

  hipLaunchKernelGGL(prep_kernel, dim3(2 * Bn + 1), dim3(256), 0, stream,
                     data, x, y, xn, celogp, total, first_occ);
  hipLaunchKernelGGL(gemm8_kernel, dim3(256), dim3(512), 0, stream,
                     (const __bf16*)xn, y, first_occ, total, posdot);
  hipLaunchKernelGGL(finalize_kernel, dim3(1), dim3(1024), 0, stream, total, posdot, celogp, out);
}

// Round 10
// 126.636 us; speedup vs baseline: 1.0097x; 1.0097x over previous
//
#include <hip/hip_runtime.h>
#include <hip/hip_bf16.h>
#include <stdint.h>

typedef __attribute__((ext_vector_type(8))) __bf16 bf16x8;
typedef __attribute__((ext_vector_type(4))) float f32x4;

constexpr int Bn = 4096;   // batch
constexpr int Dd = 1024;   // feature dim
constexpr int Cc = 1000;   // classes
constexpr int PANEL_ELEMS = 128 * Dd;   // 128-row panel (131072 elems, 256 KB)
constexpr int NTK = Dd / 64;            // 16 K-tiles of BK=64

__device__ __forceinline__ float wsum(float v) {
#pragma unroll
  for (int m = 32; m >= 1; m >>= 1) v += __shfl_xor(v, m);
  return v;
}
__device__ __forceinline__ float wmax(float v) {
#pragma unroll
  for (int m = 32; m >= 1; m >>= 1) v = fmaxf(v, __shfl_xor(v, m));
  return v;
}

// ---- fused: normalize -> tiled-bf16 xnt | CE rows | first-occurrence scan ----
// xnt layout: panel p = row>>7 (128 rows); within panel: [kt16][kk8][row128][e8]
//   kt = k>>6, kk = ((k>>5)&1)*4 + ((k>>3)&3), e = k&7.
// => each 128-row x 64-k half-tile is contiguous 16 KB, image = [kk][row][8]
//    (fragment-ready for mfma 16x16x32, conflict-free ds_read_b128; R1/R3/R9-validated).
__global__ void prep_kernel(const float* __restrict__ data, const float* __restrict__ x,
                            const int* __restrict__ y, unsigned short* __restrict__ xnt,
                            float* __restrict__ celogp, float* __restrict__ total,
                            int* __restrict__ first_occ) {
  __shared__ float red[4];
  __shared__ float red2[4];
  __shared__ int fo[Cc];
  int b = blockIdx.x;
  int t = threadIdx.x;
  if (b < Bn) {
    if (t == 0) total[b] = 0.0f;
    const float4* xr = (const float4*)(x + (size_t)b * Dd);
    float4 v = xr[t];                       // 256 threads * 4 floats
    float ss = v.x * v.x + v.y * v.y + v.z * v.z + v.w * v.w;
    ss = wsum(ss);
    if ((t & 63) == 0) red[t >> 6] = ss;
    __syncthreads();
    float inv = 1.0f / fmaxf(sqrtf(red[0] + red[1] + red[2] + red[3]), 1e-8f);
    float f[4] = {v.x * inv, v.y * inv, v.z * inv, v.w * inv};
    ushort4 o;
    unsigned short* op = (unsigned short*)&o;
#pragma unroll
    for (int k = 0; k < 4; k++) {          // f32 -> bf16 RNE
      unsigned u = __float_as_uint(f[k]);
      u += 0x7fffu + ((u >> 16) & 1u);
      op[k] = (unsigned short)(u >> 16);
    }
    int p = b >> 7, rl = b & 127;
    int k0 = t * 4;
    int kt = k0 >> 6, kk = ((k0 >> 5) & 1) * 4 + ((k0 >> 3) & 3), e = k0 & 7;  // e in {0,4}
    *(ushort4*)(xnt + (size_t)p * PANEL_ELEMS + kt * 8192 + kk * 1024 + rl * 8 + e) = o;
  } else if (b < 2 * Bn) {
    int i = b - Bn;
    const float* row = data + (size_t)i * Cc;
    float m = -1e30f;
    for (int c = t; c < Cc; c += 256) m = fmaxf(m, row[c]);
    m = wmax(m);
    if ((t & 63) == 0) red[t >> 6] = m;
    __syncthreads();
    m = fmaxf(fmaxf(red[0], red[1]), fmaxf(red[2], red[3]));
    float s = 0.f;
    for (int c = t; c < Cc; c += 256) s += __expf(row[c] - m);
    s = wsum(s);
    if ((t & 63) == 0) red2[t >> 6] = s;
    __syncthreads();
    if (t == 0) {
      float tot = red2[0] + red2[1] + red2[2] + red2[3];
      celogp[i] = -(row[y[i]] - m - logf(tot));
    }
  } else {
    for (int c = t; c < Cc; c += 256) fo[c] = 0x7fffffff;
    __syncthreads();
    for (int i = t; i < Bn; i += 256) atomicMin(&fo[y[i]], i);
    __syncthreads();
    for (int c = t; c < Cc; c += 256) first_occ[c] = fo[c];
  }
}

__device__ __forceinline__ void gload16(const void* g, void* l) {
  __builtin_amdgcn_global_load_lds((const __attribute__((address_space(1))) void*)g,
                                   (__attribute__((address_space(3))) void*)l, 16, 0, 0);
}

// ---- 8-phase 256^2 fused GEMM (T1+T3+T4+T5): S = xn @ xn^T, exp-rowsum epilogue ----
// 256 blocks (1/CU), 512 thr = 8 waves (2M x 4N). BK=64, 16 K-tiles.
// XCD 2D swizzle: xcd = blk&7 gets a 4bi x 8bj chunk (A 2MB + B 4MB working set).
// LDS 128KB: [parity2][half4: A0,A1,B0,B1][16KB]. Per tile: 4 phases, template-exact
// sync {reads | stage | barrier | lgkm(0) | prio1 16xMFMA prio0 | barrier}; NO sched_barriers.
// Stage schedule: during tile T stage ALL of tile T+2 (p1: A0,B0; p2: B1; p3: A1);
// vmcnt(8) once per tile at p3 retires tile T+1, leaves T+2's 8 loads in flight.
// Slot safety: each half staged strictly after its only read-phase (reads: A0,B0@p0, B1@p1, A1@p2).
__global__ __launch_bounds__(512, 2) void gemm8_kernel(
    const __bf16* __restrict__ xnt, const int* __restrict__ y,
    const int* __restrict__ first_occ, float* __restrict__ total,
    float* __restrict__ posdot) {
  __shared__ __align__(16) __bf16 lds[2][4][8192];
  const int t = threadIdx.x, lane = t & 63, w = t >> 6;
  const int wr = w >> 2, wc = w & 3;               // 2 x 4 wave grid
  const int xcd = blockIdx.x & 7, kb = blockIdx.x >> 3;
  const int bi = (xcd & 3) * 4 + (kb & 3);         // 4 bi per XCD
  const int bj = (xcd >> 2) * 8 + (kb >> 2);       // 8 bj per XCD
  const int kg = lane >> 4, fr = lane & 15;
  const __bf16* panA0 = xnt + (size_t)(2 * bi) * PANEL_ELEMS;
  const __bf16* panA1 = panA0 + PANEL_ELEMS;
  const __bf16* panB0 = xnt + (size_t)(2 * bj) * PANEL_ELEMS;
  const __bf16* panB1 = panB0 + PANEL_ELEMS;
  const int du = (t & ~63) * 8;                    // wave-uniform LDS dest (elems)
  const int aoff = kg * 1024 + (wr * 64 + fr) * 8; // A frag base within half
  const int boff = kg * 1024 + (wc * 32 + fr) * 8; // B frag base within half

  bf16x8 af[4][2], rb0[2][2], rb1[2][2];
  f32x4 acc[2][2][4][2] = {};

#define STAGE(pan, hs, kt, par)                                      \
  do {                                                               \
    const __bf16* s_ = (pan) + (kt) * 8192 + t * 8;                  \
    gload16(s_, &lds[par][hs][du]);                                  \
    gload16(s_ + 4096, &lds[par][hs][du + 4096]);                    \
  } while (0)
#define RDA(par, mh)                                                               \
  do {                                                                             \
    _Pragma("unroll") for (int mi = 0; mi < 4; ++mi)                               \
    _Pragma("unroll") for (int s = 0; s < 2; ++s)                                  \
      af[mi][s] = *(const bf16x8*)&lds[par][mh][aoff + s * 4096 + mi * 128];       \
  } while (0)
#define RDB(par, nh, br)                                                           \
  do {                                                                             \
    _Pragma("unroll") for (int nj = 0; nj < 2; ++nj)                               \
    _Pragma("unroll") for (int s = 0; s < 2; ++s)                                  \
      br[nj][s] = *(const bf16x8*)&lds[par][2 + nh][boff + s * 4096 + nj * 128];   \
  } while (0)
#define MM(mh, nh, br)                                                             \
  do {                                                                             \
    _Pragma("unroll") for (int mi = 0; mi < 4; ++mi)                               \
    _Pragma("unroll") for (int nj = 0; nj < 2; ++nj)                               \
    _Pragma("unroll") for (int s = 0; s < 2; ++s)                                  \
      acc[mh][nh][mi][nj] = __builtin_amdgcn_mfma_f32_16x16x32_bf16(               \
          af[mi][s], br[nj][s], acc[mh][nh][mi][nj], 0, 0, 0);                     \
  } while (0)
#define BAR() __builtin_amdgcn_s_barrier()
#define WL() asm volatile("s_waitcnt lgkmcnt(0)")
#define WV8() asm volatile("s_waitcnt vmcnt(8)")

  // ---- prologue: stage tiles 0 and 1 completely; retire tile 0 ----
  STAGE(panA0, 0, 0, 0); STAGE(panB0, 2, 0, 0); STAGE(panB1, 3, 0, 0); STAGE(panA1, 1, 0, 0);
  STAGE(panA0, 0, 1, 1); STAGE(panB0, 2, 1, 1); STAGE(panB1, 3, 1, 1); STAGE(panA1, 1, 1, 1);
  WV8();   // tile 0 resident; tile 1's 8 loads in flight
  BAR();

  // ---- main loop: 16 K-tiles x 4 phases (unroll 2 => const parity) ----
#pragma unroll 2
  for (int T = 0; T < NTK; ++T) {
    const int par = T & 1;
    const int n2 = (T + 2) & 15;                   // tile T+2 (same parity); tail wrap harmless
    // p0: reads A0,B0
    RDA(par, 0); RDB(par, 0, rb0);
    BAR(); WL();
    __builtin_amdgcn_s_setprio(1); MM(0, 0, rb0); __builtin_amdgcn_s_setprio(0);
    BAR();
    // p1: reads B1 ; stages A0(T+2), B0(T+2)   [slots last read at p0]
    RDB(par, 1, rb1);
    STAGE(panA0, 0, n2, par);
    STAGE(panB0, 2, n2, par);
    BAR(); WL();
    __builtin_amdgcn_s_setprio(1); MM(0, 1, rb1); __builtin_amdgcn_s_setprio(0);
    BAR();
    // p2: reads A1 ; stages B1(T+2)            [B1 slot last read at p1]
    RDA(par, 1);
    STAGE(panB1, 3, n2, par);
    BAR(); WL();
    __builtin_amdgcn_s_setprio(1); MM(1, 0, rb0); __builtin_amdgcn_s_setprio(0);
    BAR();
    // p3: no reads ; stages A1(T+2)            [A1 slot last read at p2] ; vmcnt(8)
    STAGE(panA1, 1, n2, par);
    __builtin_amdgcn_s_setprio(1); MM(1, 1, rb1); __builtin_amdgcn_s_setprio(0);
    WV8();   // tile T+1 fully resident; tile T+2's 8 loads stay in flight
    BAR();
  }
#undef STAGE
#undef RDA
#undef RDB
#undef MM

  // ---- epilogue: total[r] += sum_c exp(2*S[r,c]) ; posdot[c] = S[jstar[c],c] ----
  const float c2 = 2.885390081777927f;
  const int rgrp = lane >> 4, cl = lane & 15;
  int cidx[2][2], jst[2][2];
#pragma unroll
  for (int nh = 0; nh < 2; ++nh)
#pragma unroll
    for (int nj = 0; nj < 2; ++nj) {
      cidx[nh][nj] = bj * 256 + nh * 128 + wc * 32 + nj * 16 + cl;
      jst[nh][nj] = first_occ[y[cidx[nh][nj]]];
    }
#pragma unroll
  for (int mh = 0; mh < 2; ++mh)
#pragma unroll
    for (int mi = 0; mi < 4; ++mi) {
      int rb = bi * 256 + mh * 128 + wr * 64 + mi * 16 + rgrp * 4;
#pragma unroll
      for (int j = 0; j < 4; ++j) {
        int r = rb + j;
        float rs = 0.f;
#pragma unroll
        for (int nh = 0; nh < 2; ++nh)
#pragma unroll
          for (int nj = 0; nj < 2; ++nj) {
            float v = acc[mh][nh][mi][nj][j];
            rs += exp2f(v * c2);
            if (jst[nh][nj] == r) posdot[cidx[nh][nj]] = v;  // unique (r,c) globally
          }
#pragma unroll
        for (int m = 1; m <= 8; m <<= 1) rs += __shfl_xor(rs, m);  // over 16 col-lanes
        if (cl == 0) atomicAdd(&total[r], rs);
      }
    }
}

// ---- final reduction ----
__global__ void finalize_kernel(const float* __restrict__ total, const float* __restrict__ posdot,
                                const float* __restrict__ celogp, float* __restrict__ out) {
  int t = threadIdx.x;  // 1024 threads
  float fs = 0.f, cs = 0.f;
  for (int i = t; i < Bn; i += 1024) {
    fs += logf(total[i]) - 2.0f * posdot[i];
    cs += celogp[i];
  }
  fs = wsum(fs);
  cs = wsum(cs);
  __shared__ float rf[16], rc[16];
  if ((t & 63) == 0) { rf[t >> 6] = fs; rc[t >> 6] = cs; }
  __syncthreads();
  if (t == 0) {
    float lf = 0.f, la = 0.f;
#pragma unroll
    for (int w = 0; w < 16; w++) { lf += rf[w]; la += rc[w]; }
    lf /= (float)Bn;
    la /= (float)Bn;
    out[0] = la + 0.05f * lf;
    out[1] = la;
    out[2] = lf;
  }
}

extern "C" void kernel_launch(void* const* d_in, const int* in_sizes, int n_in,
                              void* d_out, int out_size, void* d_ws, size_t ws_size,
                              hipStream_t stream) {
  const float* data = (const float*)d_in[0];
  const float* x = (const float*)d_in[1];
  const int* y = (const int*)d_in[2];
  char* ws = (char*)d_ws;
  unsigned short* xn = (unsigned short*)ws;                       // 8 MB bf16, tiled layout
  float* total = (float*)(ws + (size_t)8 * 1024 * 1024);          // 16 KB
  float* posdot = total + Bn;                                     // 16 KB
  float* celogp = posdot + Bn;                                    // 16 KB
  int* first_occ = (int*)(celogp + Bn);                           // 4 KB
  float* out = (float*)d_out;

  hipLaunchKernelGGL(prep_kernel, dim3(2 * Bn + 1), dim3(256), 0, stream,
                     data, x, y, xn, celogp, total, first_occ);
  hipLaunchKernelGGL(gemm8_kernel, dim3(256), dim3(512), 0, stream,
                     (const __bf16*)xn, y, first_occ, total, posdot);
  hipLaunchKernelGGL(finalize_kernel, dim3(1), dim3(1024), 0, stream, total, posdot, celogp, out);
}

// Round 11
// 113.082 us; speedup vs baseline: 1.1307x; 1.1199x over previous
//
#include <hip/hip_runtime.h>
#include <hip/hip_bf16.h>
#include <stdint.h>

typedef __attribute__((ext_vector_type(8))) int i32x8;
typedef __attribute__((ext_vector_type(4))) float f32x4;

constexpr int Bn = 4096;   // batch
constexpr int Dd = 1024;   // feature dim
constexpr int Cc = 1000;   // classes
constexpr int NPANEL = 32;               // Bn / 128
constexpr int PANEL_BYTES = 128 * 1024;  // 128 rows x 1024 k x 1B fp8
constexpr int NK8 = Dd / 128;            // 8 K-tiles of BK=128

__device__ __forceinline__ float wsum(float v) {
#pragma unroll
  for (int m = 32; m >= 1; m >>= 1) v += __shfl_xor(v, m);
  return v;
}
__device__ __forceinline__ float wmax(float v) {
#pragma unroll
  for (int m = 32; m >= 1; m >>= 1) v = fmaxf(v, __shfl_xor(v, m));
  return v;
}

// f32 -> OCP e4m3fn, round-to-nearest-even. |f| <= ~1 here (normalized rows).
__device__ __forceinline__ unsigned f32_to_e4m3(float f) {
  float a = fabsf(f);
  unsigned s = (__float_as_uint(f) >> 24) & 0x80u;
  if (a < 0.015625f) {                       // subnormal: s * 2^-9, s in [0,8) (8 rolls to 2^-6 encoding)
    int q = (int)rintf(a * 512.0f);
    return s | (unsigned)q;
  }
  unsigned u = __float_as_uint(a);
  unsigned E = (u >> 23) - 120u;             // e4m3 exponent field (bias 7)
  unsigned m = (u >> 20) & 7u;
  unsigned rem = u & 0xFFFFFu;
  unsigned enc = (E << 3) | m;
  enc += (rem > 0x80000u) || (rem == 0x80000u && (m & 1u));  // RNE, carry ok
  return s | enc;
}

// ---- fused: normalize -> tiled-fp8 xnq | CE rows | first-occurrence scan ----
// xnq layout: panel p = row>>7 (128 rows, 128KB); within panel: [kt8][kg4][row128][b32]
//   kt = k>>7, kg = (k>>5)&3, b = k&31.
// => each 128-row x 128-k tile is contiguous 16KB, image = [kg][row][32B]
//    (fragment-ready for mfma 16x16x128: lane reads 32 consecutive-k bytes at
//     kg*4096 + row*32 — same consecutive-chunk pattern as the validated bf16 layout).
__global__ void prep_kernel(const float* __restrict__ data, const float* __restrict__ x,
                            const int* __restrict__ y, unsigned char* __restrict__ xnq,
                            float* __restrict__ celogp, float* __restrict__ total,
                            int* __restrict__ first_occ) {
  __shared__ float red[4];
  __shared__ float red2[4];
  __shared__ int fo[Cc];
  int b = blockIdx.x;
  int t = threadIdx.x;
  if (b < Bn) {
    if (t == 0) total[b] = 0.0f;
    const float4* xr = (const float4*)(x + (size_t)b * Dd);
    float4 v = xr[t];                       // 256 threads * 4 floats
    float ss = v.x * v.x + v.y * v.y + v.z * v.z + v.w * v.w;
    ss = wsum(ss);
    if ((t & 63) == 0) red[t >> 6] = ss;
    __syncthreads();
    float inv = 1.0f / fmaxf(sqrtf(red[0] + red[1] + red[2] + red[3]), 1e-8f);
    unsigned q0 = f32_to_e4m3(v.x * inv);
    unsigned q1 = f32_to_e4m3(v.y * inv);
    unsigned q2 = f32_to_e4m3(v.z * inv);
    unsigned q3 = f32_to_e4m3(v.w * inv);
    unsigned w = q0 | (q1 << 8) | (q2 << 16) | (q3 << 24);
    int p = b >> 7, rl = b & 127;
    int kt = t >> 5, kg = (t >> 3) & 3;     // k0 = t*4
    unsigned* xq = (unsigned*)(xnq + (size_t)p * PANEL_BYTES);
    xq[kt * 4096 + kg * 1024 + rl * 8 + (t & 7)] = w;
  } else if (b < 2 * Bn) {
    int i = b - Bn;
    const float* row = data + (size_t)i * Cc;
    float m = -1e30f;
    for (int c = t; c < Cc; c += 256) m = fmaxf(m, row[c]);
    m = wmax(m);
    if ((t & 63) == 0) red[t >> 6] = m;
    __syncthreads();
    m = fmaxf(fmaxf(red[0], red[1]), fmaxf(red[2], red[3]));
    float s = 0.f;
    for (int c = t; c < Cc; c += 256) s += __expf(row[c] - m);
    s = wsum(s);
    if ((t & 63) == 0) red2[t >> 6] = s;
    __syncthreads();
    if (t == 0) {
      float tot = red2[0] + red2[1] + red2[2] + red2[3];
      celogp[i] = -(row[y[i]] - m - logf(tot));
    }
  } else {
    for (int c = t; c < Cc; c += 256) fo[c] = 0x7fffffff;
    __syncthreads();
    for (int i = t; i < Bn; i += 256) atomicMin(&fo[y[i]], i);
    __syncthreads();
    for (int c = t; c < Cc; c += 256) first_occ[c] = fo[c];
  }
}

__device__ __forceinline__ void gload16(const void* g, void* l) {
  __builtin_amdgcn_global_load_lds((const __attribute__((address_space(1))) void*)g,
                                   (__attribute__((address_space(3))) void*)l, 16, 0, 0);
}

// ---- fp8 K=128 symmetric S = xn @ xn^T, upper-triangle tiles (R3-proven 2-phase dbuf) ----
// 128x128 tile, 4 waves (2x2 of 64x64), BK=128, v_mfma_f32_16x16x128_f8f6f4 (e4m3, scale=1).
// LDS 64KB: [buf2][A/B][16KB]. 8 K-iters: prefetch next tile into other buffer, one barrier/iter.
// k-permutation within fragments cancels in A·A^T (identical A/B images); C/D mapping is the
// validated shape-determined 16x16 layout. XCD chunking: 528 = 8 x 66 (bijective).
// Epilogue: exp(2S) row-sums (+ mirrored col-sums off-diag) into total[]; posdot[c]=S[jstar[c],c].
__global__ __launch_bounds__(256, 2) void gemm_fp8_kernel(
    const unsigned char* __restrict__ xnq, const int* __restrict__ y,
    const int* __restrict__ first_occ, float* __restrict__ total,
    float* __restrict__ posdot) {
  __shared__ __align__(16) unsigned char lds[2][2][16384];
  int t = threadIdx.x, lane = t & 63, wave = t >> 6;
  int wr = wave >> 1, wc = wave & 1;
  // XCD-chunked block id -> upper-triangle (bi <= bj)
  int id = (blockIdx.x & 7) * 66 + (blockIdx.x >> 3);
  int bi = 0, rem = id;
  while (rem >= NPANEL - bi) { rem -= NPANEL - bi; ++bi; }
  int bj = bi + rem;
  const unsigned char* pa = xnq + (size_t)bi * PANEL_BYTES;
  const unsigned char* pb = xnq + (size_t)bj * PANEL_BYTES;
  int kg = lane >> 4, fr = lane & 15;
  int aoff = kg * 4096 + (wr * 64 + fr) * 32;
  int boff = kg * 4096 + (wc * 64 + fr) * 32;
  f32x4 acc[4][4] = {};

#define STAGE(buf, kt)                                                        \
  do {                                                                        \
    const unsigned char* ta = pa + (kt) * 16384;                              \
    const unsigned char* tb = pb + (kt) * 16384;                              \
    _Pragma("unroll") for (int s = 0; s < 4; ++s) {                           \
      int ub = s * 4096 + (t & ~63) * 16; /* wave-uniform dest base */        \
      gload16(ta + s * 4096 + t * 16, &lds[buf][0][ub]);                      \
      gload16(tb + s * 4096 + t * 16, &lds[buf][1][ub]);                      \
    }                                                                         \
  } while (0)

  STAGE(0, 0);
  __syncthreads();
  int cur = 0;
  for (int kt = 0; kt < NK8; ++kt) {
    if (kt + 1 < NK8) STAGE(cur ^ 1, kt + 1);   // prefetch next K-tile into other buffer
    i32x8 af[4], bg[4];
#pragma unroll
    for (int mi = 0; mi < 4; mi++) af[mi] = *(const i32x8*)&lds[cur][0][aoff + mi * 512];
#pragma unroll
    for (int nj = 0; nj < 4; nj++) bg[nj] = *(const i32x8*)&lds[cur][1][boff + nj * 512];
#pragma unroll
    for (int mi = 0; mi < 4; mi++)
#pragma unroll
      for (int nj = 0; nj < 4; nj++)
        asm("v_mfma_f32_16x16x128_f8f6f4 %0, %1, %2, %0"
            : "+v"(acc[mi][nj])
            : "v"(af[mi]), "v"(bg[nj]));
    __syncthreads();   // drains staging vmcnt + frag lgkm; buffers swap
    cur ^= 1;
  }
#undef STAGE

  // epilogue: exp(2s) = exp2(s * 2*log2(e))
  const float c2 = 2.885390081777927f;
  int arow0 = bi * 128, brow0 = bj * 128;
  int rgrp = lane >> 4, cl = lane & 15;
  int cidx[4], jst[4];
  float colsum[4] = {0.f, 0.f, 0.f, 0.f};
#pragma unroll
  for (int nj = 0; nj < 4; nj++) {
    cidx[nj] = brow0 + wc * 64 + nj * 16 + cl;
    jst[nj] = first_occ[y[cidx[nj]]];
  }
#pragma unroll
  for (int mi = 0; mi < 4; mi++) {
    int rb = arow0 + wr * 64 + mi * 16 + rgrp * 4;
#pragma unroll
    for (int reg = 0; reg < 4; reg++) {
      int r = rb + reg;
      float rs = 0.f;
#pragma unroll
      for (int nj = 0; nj < 4; nj++) {
        float v = acc[mi][nj][reg];
        float e = exp2f(v * c2);
        rs += e;
        colsum[nj] += e;
        if (jst[nj] == r) posdot[cidx[nj]] = v;   // unique position per column
      }
#pragma unroll
      for (int m = 1; m <= 8; m <<= 1) rs += __shfl_xor(rs, m);  // over 16 col-lanes
      if (cl == 0) atomicAdd(&total[r], rs);
    }
  }
  if (bi != bj) {   // off-diagonal: column sums are the mirrored rows' contributions
#pragma unroll
    for (int nj = 0; nj < 4; nj++) {
      float cs = colsum[nj];
      cs += __shfl_xor(cs, 16);
      cs += __shfl_xor(cs, 32);
      if (lane < 16) atomicAdd(&total[cidx[nj]], cs);
    }
  }
}

// ---- final reduction ----
__global__ void finalize_kernel(const float* __restrict__ total, const float* __restrict__ posdot,
                                const float* __restrict__ celogp, float* __restrict__ out) {
  int t = threadIdx.x;  // 1024 threads
  float fs = 0.f, cs = 0.f;
  for (int i = t; i < Bn; i += 1024) {
    fs += logf(total[i]) - 2.0f * posdot[i];
    cs += celogp[i];
  }
  fs = wsum(fs);
  cs = wsum(cs);
  __shared__ float rf[16], rc[16];
  if ((t & 63) == 0) { rf[t >> 6] = fs; rc[t >> 6] = cs; }
  __syncthreads();
  if (t == 0) {
    float lf = 0.f, la = 0.f;
#pragma unroll
    for (int w = 0; w < 16; w++) { lf += rf[w]; la += rc[w]; }
    lf /= (float)Bn;
    la /= (float)Bn;
    out[0] = la + 0.05f * lf;
    out[1] = la;
    out[2] = lf;
  }
}

extern "C" void kernel_launch(void* const* d_in, const int* in_sizes, int n_in,
                              void* d_out, int out_size, void* d_ws, size_t ws_size,
                              hipStream_t stream) {
  const float* data = (const float*)d_in[0];
  const float* x = (const float*)d_in[1];
  const int* y = (const int*)d_in[2];
  char* ws = (char*)d_ws;
  unsigned char* xnq = (unsigned char*)ws;                        // 4 MB fp8, tiled layout
  float* total = (float*)(ws + (size_t)8 * 1024 * 1024);          // 16 KB
  float* posdot = total + Bn;                                     // 16 KB
  float* celogp = posdot + Bn;                                    // 16 KB
  int* first_occ = (int*)(celogp + Bn);                           // 4 KB
  float* out = (float*)d_out;

  hipLaunchKernelGGL(prep_kernel, dim3(2 * Bn + 1), dim3(256), 0, stream,
                     data, x, y, xnq, celogp, total, first_occ);
  hipLaunchKernelGGL(gemm_fp8_kernel, dim3(NPANEL * (NPANEL + 1) / 2), dim3(256), 0, stream,
                     xnq, y, first_occ, total, posdot);
  hipLaunchKernelGGL(finalize_kernel, dim3(1), dim3(1024), 0, stream, total, posdot, celogp, out);
}